// Round 6
// baseline (550.589 us; speedup 1.0000x reference)
//
#include <hip/hip_runtime.h>
#include <hip/hip_bf16.h>
#include <math.h>

typedef unsigned short u16;
typedef short bf16x8 __attribute__((ext_vector_type(8)));
typedef float f32x4 __attribute__((ext_vector_type(4)));

#define LN2F 0.693147180559945f

__device__ __forceinline__ float bf2f(u16 h) {
  union { unsigned int i; float f; } v; v.i = ((unsigned int)h) << 16; return v.f;
}
__device__ __forceinline__ u16 f2bf(float f) {
  union { float f; unsigned int i; } v; v.f = f;
  unsigned int x = v.i;
  return (u16)((x + 0x7fffu + ((x >> 16) & 1u)) >> 16);
}
// shifted softplus via HW transcendentals (v_exp_f32 + v_log_f32).
__device__ __forceinline__ float sspf(float v) {
  return fmaxf(v, 0.0f) + __logf(1.0f + __expf(-fabsf(v))) - LN2F;
}

// ---------------------------------------------------------------------------
// Dtype probe: bf16 N(0,1) data never has bf16-exponent >= 0xC0; f32 data
// misread as u16 halfwords certainly does.  0 = bf16 inputs, 1 = f32 inputs.
// ---------------------------------------------------------------------------
__global__ void probe_k(const u16* __restrict__ x, int* __restrict__ flag) {
  __shared__ int sf;
  if (threadIdx.x == 0) sf = 0;
  __syncthreads();
  int f = 0;
  for (int i = threadIdx.x; i < 4096; i += 256) {
    const unsigned e = (x[i] >> 7) & 0xFFu;
    if (e >= 0xC0u) f = 1;
  }
  if (f) atomicOr(&sf, 1);
  __syncthreads();
  if (threadIdx.x == 0) *flag = sf;
}

// ---------------------------------------------------------------------------
// Linear 16B-chunk copy (global -> LDS), 256 threads; conflict-free.
// ---------------------------------------------------------------------------
template<int NB>
__device__ __forceinline__ void copy_lin(const u16* __restrict__ g, u16* s, int tid) {
  constexpr int CH = NB / 16;
#pragma unroll
  for (int c = tid; c < CH; c += 256)
    *(bf16x8*)(s + (size_t)c * 8) = *(const bf16x8*)(g + (size_t)c * 8);
}

// 128x136 u16 weight buffer = 2176 16B chunks: reg-staged split (issue loads
// early, ds_write late -> L2 latency hides under activation VALU work).
__device__ __forceinline__ void wload(const u16* __restrict__ g, bf16x8* w, int tid) {
#pragma unroll
  for (int p = 0; p < 8; ++p) w[p] = *(const bf16x8*)(g + (size_t)(tid + p * 256) * 8);
  if (tid < 128) w[8] = *(const bf16x8*)(g + (size_t)(2048 + tid) * 8);
}
__device__ __forceinline__ void wstore(u16* s, const bf16x8* w, int tid) {
#pragma unroll
  for (int p = 0; p < 8; ++p) *(bf16x8*)(s + (size_t)(tid + p * 256) * 8) = w[p];
  if (tid < 128) *(bf16x8*)(s + (size_t)(2048 + tid) * 8) = w[8];
}

// MFMA sweep: acc[t] += sA_strip[m16][k] * sW[t*16+m16][k]
template<int KSTEPS, int LDW>
__device__ __forceinline__ void mm_lds(const u16* sA, const u16* sW, f32x4* acc,
                                       int m16, int quad) {
#pragma unroll
  for (int s = 0; s < KSTEPS; ++s) {
    const int k0 = s * 32 + quad * 8;
    bf16x8 a = *(const bf16x8*)(sA + (size_t)m16 * LDW + k0);
#pragma unroll
    for (int t = 0; t < 8; ++t) {
      bf16x8 b = *(const bf16x8*)(sW + (size_t)(t * 16 + m16) * LDW + k0);
      acc[t] = __builtin_amdgcn_mfma_f32_16x16x32_bf16(a, b, acc[t], 0, 0, 0);
    }
  }
}

// ---------------------------------------------------------------------------
// prep_k: transpose + bf16-convert every weight matrix ONCE into WT (padded).
// WT layout (u16 units): [0]=WiT [17408]=WjT [2*17408]=WfT
//   [ (3+l)*17408 ]   = Wr1T[l]   (each [128][136])
//   [ (3+L+l)*17408 ] = Wr2T[l]
//   [ (3+2L)*17408 ]  = Wk2fT    ([128][72])
// Runtime mode; dtype-dependent loads inside real branches (alternate-dtype
// address ranges can be OOB -> must not be speculated).
// ---------------------------------------------------------------------------
__global__ __launch_bounds__(256) void prep_k(
    const int* __restrict__ mode,
    const void* __restrict__ Wi, const void* __restrict__ Wj,
    const void* __restrict__ Wf, const void* __restrict__ Wk2f,
    const void* __restrict__ Wr1, const void* __restrict__ Wr2,
    u16* __restrict__ WT, int L)
{
  const int md = *mode;
  const int b = blockIdx.x, tid = threadIdx.x;
  const size_t esz = md ? 4 : 2;
  const void* src; u16* dst; int KD = 128, LDW = 136;
  if      (b == 0) { src = Wi;  dst = WT; }
  else if (b == 1) { src = Wj;  dst = WT + 17408; }
  else if (b == 2) { src = Wf;  dst = WT + 2 * 17408; }
  else if (b == 3) { src = Wk2f; dst = WT + (size_t)(3 + 2 * L) * 17408; KD = 64; LDW = 72; }
  else if (b < 4 + L) { int l = b - 4;     src = (const char*)Wr1 + (size_t)l * 16384 * esz; dst = WT + (size_t)(3 + l) * 17408; }
  else                { int l = b - 4 - L; src = (const char*)Wr2 + (size_t)l * 16384 * esz; dst = WT + (size_t)(3 + L + l) * 17408; }

  const int n  = tid & 127;
  const int kh = (tid >> 7) * (KD >> 1);
  if (md == 0) {
    for (int c = 0; c < (KD >> 4); ++c) {
      const int k0 = kh + c * 8;
      bf16x8 rv;
#pragma unroll
      for (int j = 0; j < 8; ++j)
        rv[j] = (short)((const u16*)src)[(size_t)(k0 + j) * 128 + n];
      *(bf16x8*)(dst + (size_t)n * LDW + k0) = rv;
    }
  } else {
    for (int c = 0; c < (KD >> 4); ++c) {
      const int k0 = kh + c * 8;
      bf16x8 rv;
#pragma unroll
      for (int j = 0; j < 8; ++j)
        rv[j] = (short)f2bf(((const float*)src)[(size_t)(k0 + j) * 128 + n]);
      *(bf16x8*)(dst + (size_t)n * LDW + k0) = rv;
    }
  }
}

// ---------------------------------------------------------------------------
// in_k: fused xi/xj input GEMMs.  A = ssp(x) fragments held in regs once.
//   mb  = xi     = ssp(ssp(x)@Wi + bi)   [f32]
//   xjt = xj_all = ssp(ssp(x)@Wj + bj)   [bf16]
// Wj is reg-prefetched during the Wi MFMA sweep.
// ---------------------------------------------------------------------------
__global__ __launch_bounds__(256) void in_k(
    const int* __restrict__ mode, const void* __restrict__ x,
    const u16* __restrict__ WiT, const u16* __restrict__ WjT,
    const void* __restrict__ bi, const void* __restrict__ bj,
    float* __restrict__ mb, u16* __restrict__ xjt, int N)
{
  const int md = *mode;
  __shared__ u16 sW[128 * 136];
  const int tid = threadIdx.x, lane = tid & 63, wave = tid >> 6;
  const int m16 = lane & 15, quad = lane >> 4;
  const int row_tile = blockIdx.x * 64 + wave * 16;
  int arow = row_tile + m16; if (arow >= N) arow = N - 1;

  bf16x8 af[4];
  if (md == 0) {
#pragma unroll
    for (int s = 0; s < 4; ++s) {
      const int k0 = s * 32 + quad * 8;
      bf16x8 raw = *(const bf16x8*)((const u16*)x + (size_t)arow * 128 + k0);
#pragma unroll
      for (int j = 0; j < 8; ++j) af[s][j] = (short)f2bf(sspf(bf2f((u16)raw[j])));
    }
  } else {
#pragma unroll
    for (int s = 0; s < 4; ++s) {
      const int k0 = s * 32 + quad * 8;
      const float* ap = (const float*)x + (size_t)arow * 128 + k0;
      float4 lo = *(const float4*)ap, hi = *(const float4*)(ap + 4);
      float v[8] = {lo.x, lo.y, lo.z, lo.w, hi.x, hi.y, hi.z, hi.w};
#pragma unroll
      for (int j = 0; j < 8; ++j) af[s][j] = (short)f2bf(sspf(v[j]));
    }
  }

  copy_lin<128 * 136 * 2>(WiT, sW, tid);
  __syncthreads();
  f32x4 aI[8], aJ[8];
#pragma unroll
  for (int t = 0; t < 8; ++t) aI[t] = (f32x4){0.f, 0.f, 0.f, 0.f};
  bf16x8 w[9];
  wload(WjT, w, tid);                 // prefetch Wj under the Wi sweep
#pragma unroll
  for (int s = 0; s < 4; ++s) {
    const int k0 = s * 32 + quad * 8;
#pragma unroll
    for (int t = 0; t < 8; ++t) {
      bf16x8 b = *(const bf16x8*)(sW + (size_t)(t * 16 + m16) * 136 + k0);
      aI[t] = __builtin_amdgcn_mfma_f32_16x16x32_bf16(af[s], b, aI[t], 0, 0, 0);
    }
  }
  __syncthreads();
  wstore(sW, w, tid);
  __syncthreads();
#pragma unroll
  for (int t = 0; t < 8; ++t) aJ[t] = (f32x4){0.f, 0.f, 0.f, 0.f};
#pragma unroll
  for (int s = 0; s < 4; ++s) {
    const int k0 = s * 32 + quad * 8;
#pragma unroll
    for (int t = 0; t < 8; ++t) {
      bf16x8 b = *(const bf16x8*)(sW + (size_t)(t * 16 + m16) * 136 + k0);
      aJ[t] = __builtin_amdgcn_mfma_f32_16x16x32_bf16(af[s], b, aJ[t], 0, 0, 0);
    }
  }

#pragma unroll
  for (int t = 0; t < 8; ++t) {
    const int col = t * 16 + m16;
    float biv, bjv;
    if (md == 0) { biv = bf2f(((const u16*)bi)[col]); bjv = bf2f(((const u16*)bj)[col]); }
    else         { biv = ((const float*)bi)[col];     bjv = ((const float*)bj)[col]; }
#pragma unroll
    for (int r = 0; r < 4; ++r) {
      const int ro = row_tile + quad * 4 + r;
      if (ro >= N) continue;
      const size_t off = (size_t)ro * 128 + col;
      mb[off]  = sspf(aI[t][r] + biv);
      xjt[off] = f2bf(sspf(aJ[t][r] + bjv));
    }
  }
}

// ---------------------------------------------------------------------------
// edge_k: one 64-edge tile per block (12500 blocks -> max TLP).  All loads
// issued up-front; B-fragments (Wk2f^T, 18.4 KB shared by ALL blocks ->
// L1-resident per CU) are streamed STRAIGHT FROM GLOBAL -- no LDS weight
// staging, no staging regs, no staging barrier.  msg = g*xj computed in
// registers; only the scan transpose goes through LDS.
// LDS: sMsg 16896 + sIi 256 = 17152 B; __launch_bounds__(256,6) caps VGPR
// at ~85 -> ~6 blocks/CU (was 4) -> higher rbf-load duty cycle.
// ---------------------------------------------------------------------------
__global__ __launch_bounds__(256, 6) void edge_k(
    const int* __restrict__ mode,
    const void* __restrict__ rbf, const u16* __restrict__ WkT,
    const u16* __restrict__ xj_all, const int* __restrict__ idx_i,
    const int* __restrict__ idx_j, float* __restrict__ mb, int E)
{
  const int md = *mode;
  __shared__ u16 sMsg[64][132];
  __shared__ int sIi[64];
  const int tid = threadIdx.x;
  const int e0 = blockIdx.x * 64;
  const int lane = tid & 63, wave = tid >> 6;
  const int m16 = lane & 15, quad = lane >> 4;
  const int lebase = wave * 16 + quad * 4;   // this lane's 4 owned edge rows

  if (tid < 64) sIi[tid] = (e0 + tid < E) ? idx_i[e0 + tid] : -1;
  int jrow[4];
#pragma unroll
  for (int r = 0; r < 4; ++r) {
    const int e = e0 + lebase + r;
    jrow[r] = (e < E) ? idx_j[e] : 0;        // broadcast-cached 4B loads
  }

  // rbf A-fragments into regs (convert to bf16 at load in f32 mode)
  int er = e0 + wave * 16 + m16; if (er >= E) er = E - 1;
  bf16x8 rb[2];
  if (md == 0) {
    const u16* p = (const u16*)rbf + (size_t)er * 64 + quad * 8;
    rb[0] = *(const bf16x8*)p;
    rb[1] = *(const bf16x8*)(p + 32);
  } else {
    const float* p = (const float*)rbf + (size_t)er * 64 + quad * 8;
    float4 a0 = *(const float4*)p,        a1 = *(const float4*)(p + 4);
    float4 a2 = *(const float4*)(p + 32), a3 = *(const float4*)(p + 36);
    rb[0][0] = f2bf(a0.x); rb[0][1] = f2bf(a0.y); rb[0][2] = f2bf(a0.z); rb[0][3] = f2bf(a0.w);
    rb[0][4] = f2bf(a1.x); rb[0][5] = f2bf(a1.y); rb[0][6] = f2bf(a1.z); rb[0][7] = f2bf(a1.w);
    rb[1][0] = f2bf(a2.x); rb[1][1] = f2bf(a2.y); rb[1][2] = f2bf(a2.z); rb[1][3] = f2bf(a2.w);
    rb[1][4] = f2bf(a3.x); rb[1][5] = f2bf(a3.y); rb[1][6] = f2bf(a3.z); rb[1][7] = f2bf(a3.w);
  }

  // gather xj directly in C-fragment layout (32 x 2B per lane, L2/L3-hot)
  u16 xg[8][4];
#pragma unroll
  for (int r = 0; r < 4; ++r) {
    const u16* xr = xj_all + (size_t)jrow[r] * 128 + m16;
#pragma unroll
    for (int t = 0; t < 8; ++t) xg[t][r] = xr[t * 16];
  }

  // MFMA: g = rbf @ Wk2f, B-fragments streamed from global (L1-hot)
  f32x4 acc[8];
#pragma unroll
  for (int t = 0; t < 8; ++t) acc[t] = (f32x4){0.f, 0.f, 0.f, 0.f};
  const u16* wp = WkT + (size_t)m16 * 72 + quad * 8;
#pragma unroll
  for (int s = 0; s < 2; ++s) {
#pragma unroll
    for (int t = 0; t < 8; ++t) {
      bf16x8 b = *(const bf16x8*)(wp + (size_t)(t * 16) * 72 + s * 32);
      acc[t] = __builtin_amdgcn_mfma_f32_16x16x32_bf16(rb[s], b, acc[t], 0, 0, 0);
    }
  }

  // msg = g * xj in registers; write owner slots to sMsg for the scan
#pragma unroll
  for (int t = 0; t < 8; ++t) {
    const int col = t * 16 + m16;
#pragma unroll
    for (int r = 0; r < 4; ++r) {
      const float xvf = (e0 + lebase + r < E) ? bf2f(xg[t][r]) : 0.f;
      sMsg[lebase + r][col] = f2bf(acc[t][r] * xvf);
    }
  }
  __syncthreads();

  // segment scan over sorted idx_i; boundary atomics
  const int scol = tid & 127;
  const int sbeg = (tid >> 7) * 32;
  float sum = 0.f;
  int cur = sIi[sbeg];
#pragma unroll 4
  for (int r = 0; r < 32; ++r) {
    const int node = sIi[sbeg + r];
    if (node != cur) {
      if (cur >= 0) atomicAdd(&mb[(size_t)cur * 128 + scol], sum);
      sum = 0.f; cur = node;
    }
    sum += bf2f(sMsg[sbeg + r][scol]);
  }
  if (cur >= 0) atomicAdd(&mb[(size_t)cur * 128 + scol], sum);
}

// ---------------------------------------------------------------------------
// resid_k: fused residual chain + final output, 64 rows/block (782 blocks,
// 52224 B LDS -> 3 blocks/CU).  m stays in MFMA C-fragments.  Per phase:
// issue next weight's global loads -> ssp into sM -> ds_write weight ->
// barrier -> MFMA sweep.  Load latency hides under ssp.
// ---------------------------------------------------------------------------
__global__ __launch_bounds__(256) void resid_k(
    const int* __restrict__ mode, const float* __restrict__ mb,
    const u16* __restrict__ WT,
    const void* __restrict__ br1, const void* __restrict__ br2,
    const void* __restrict__ bfv, const void* __restrict__ x,
    const void* __restrict__ u, void* __restrict__ out, int N, int L)
{
  const int md = *mode;
  __shared__ u16 sW[128 * 136];
  __shared__ u16 sM[64 * 136];
  const int tid = threadIdx.x, lane = tid & 63, wave = tid >> 6;
  const int m16 = lane & 15, quad = lane >> 4;
  const int rbase = blockIdx.x * 64 + wave * 16 + quad * 4;
  u16* sMw = sM + (size_t)(wave * 16) * 136;   // wave's 16-row strip

  f32x4 m[8];
#pragma unroll
  for (int t = 0; t < 8; ++t) {
    const int col = t * 16 + m16;
#pragma unroll
    for (int r = 0; r < 4; ++r) {
      int ro = rbase + r; if (ro >= N) ro = N - 1;
      m[t][r] = mb[(size_t)ro * 128 + col];
    }
  }

  const u16* W1T = WT + (size_t)3 * 17408;
  const u16* W2T = WT + (size_t)(3 + L) * 17408;
  bf16x8 w[9];

  for (int l = 0; l < L; ++l) {
    // phase A: sM := ssp(m); sW := W1 (loads issued before the ssp block)
    wload(W1T + (size_t)l * 17408, w, tid);
#pragma unroll
    for (int t = 0; t < 8; ++t) {
      const int col = t * 16 + m16;
#pragma unroll
      for (int r = 0; r < 4; ++r)
        sM[(size_t)(wave * 16 + quad * 4 + r) * 136 + col] = f2bf(sspf(m[t][r]));
    }
    wstore(sW, w, tid);
    __syncthreads();

    f32x4 a1[8];
#pragma unroll
    for (int t = 0; t < 8; ++t) a1[t] = (f32x4){0.f, 0.f, 0.f, 0.f};
    mm_lds<4, 136>(sMw, sW, a1, m16, quad);
    __syncthreads();

    // phase B: sM := ssp(a1 + b1); sW := W2
    wload(W2T + (size_t)l * 17408, w, tid);
#pragma unroll
    for (int t = 0; t < 8; ++t) {
      const int col = t * 16 + m16;
      float b1v;
      if (md == 0) b1v = bf2f(((const u16*)br1)[(size_t)l * 128 + col]);
      else         b1v = ((const float*)br1)[(size_t)l * 128 + col];
#pragma unroll
      for (int r = 0; r < 4; ++r)
        sM[(size_t)(wave * 16 + quad * 4 + r) * 136 + col] = f2bf(sspf(a1[t][r] + b1v));
    }
    wstore(sW, w, tid);
    __syncthreads();

    mm_lds<4, 136>(sMw, sW, m, m16, quad);   // m += t1 @ W2
#pragma unroll
    for (int t = 0; t < 8; ++t) {
      float b2v;
      if (md == 0) b2v = bf2f(((const u16*)br2)[(size_t)l * 128 + t * 16 + m16]);
      else         b2v = ((const float*)br2)[(size_t)l * 128 + t * 16 + m16];
#pragma unroll
      for (int r = 0; r < 4; ++r) m[t][r] += b2v;
    }
    __syncthreads();   // reads done before next phase's staging
  }

  // final: out = u*x + ssp(m)@Wf + bf
  wload(WT + (size_t)2 * 17408, w, tid);   // WfT
#pragma unroll
  for (int t = 0; t < 8; ++t) {
    const int col = t * 16 + m16;
#pragma unroll
    for (int r = 0; r < 4; ++r)
      sM[(size_t)(wave * 16 + quad * 4 + r) * 136 + col] = f2bf(sspf(m[t][r]));
  }
  wstore(sW, w, tid);
  __syncthreads();

  f32x4 o[8];
#pragma unroll
  for (int t = 0; t < 8; ++t) o[t] = (f32x4){0.f, 0.f, 0.f, 0.f};
  mm_lds<4, 136>(sMw, sW, o, m16, quad);

#pragma unroll
  for (int t = 0; t < 8; ++t) {
    const int col = t * 16 + m16;
    float bv, uvv;
    if (md == 0) { bv = bf2f(((const u16*)bfv)[col]); uvv = bf2f(((const u16*)u)[col]); }
    else         { bv = ((const float*)bfv)[col];     uvv = ((const float*)u)[col]; }
#pragma unroll
    for (int r = 0; r < 4; ++r) {
      const int ro = rbase + r;
      if (ro >= N) continue;
      const size_t off = (size_t)ro * 128 + col;
      if (md == 0) ((u16*)out)[off]  = f2bf(uvv * bf2f(((const u16*)x)[off]) + o[t][r] + bv);
      else         ((float*)out)[off] = uvv * ((const float*)x)[off] + o[t][r] + bv;
    }
  }
}

// ---------------------------------------------------------------------------
extern "C" void kernel_launch(void* const* d_in, const int* in_sizes, int n_in,
                              void* d_out, int out_size, void* d_ws, size_t ws_size,
                              hipStream_t stream)
{
  const void* x    = d_in[0];
  const void* rbf  = d_in[1];
  const void* Wk2f = d_in[2];
  const void* Wi   = d_in[3];
  const void* bi   = d_in[4];
  const void* Wj   = d_in[5];
  const void* bj   = d_in[6];
  const void* Wr1  = d_in[7];
  const void* br1  = d_in[8];
  const void* Wr2  = d_in[9];
  const void* br2  = d_in[10];
  const void* Wf   = d_in[11];
  const void* bfv  = d_in[12];
  const void* uv   = d_in[13];
  const int* idx_i = (const int*)d_in[14];
  const int* idx_j = (const int*)d_in[15];

  const int N = in_sizes[0] / 128;
  const int E = in_sizes[14];
  const int L = in_sizes[7] / (128 * 128);

  int* flag = (int*)d_ws;
  char* wsb = (char*)d_ws + 16;
  const size_t avail = ws_size > 16 ? ws_size - 16 : 0;

  // pre-transposed weight area (bf16, padded strides)
  const size_t needW  = ((size_t)(3 + 2 * L) * 17408 + 9216) * 2;
  const size_t needWA = (needW + 255) & ~(size_t)255;
  u16* WT = (u16*)wsb;
  char* wsb2 = wsb + needWA;
  const size_t avail2 = (avail > needWA) ? avail - needWA : 0;

  const size_t needF = (size_t)N * 512;   // mb f32
  const size_t needH = (size_t)N * 256;   // xj_all bf16

  float* mb; u16* xjt;
  if (avail2 >= needF + needH) { mb = (float*)wsb2; xjt = (u16*)(wsb2 + needF); }
  else if (avail2 >= needF)    { mb = (float*)wsb2; xjt = (u16*)d_out; }
  else                         { mb = (float*)d_out; xjt = (u16*)wsb2; }

  const dim3 blk(256);
  const int gridN = (N + 63) / 64;
  const int gridE = (E + 63) / 64;

  probe_k<<<1, 256, 0, stream>>>((const u16*)x, flag);
  prep_k<<<4 + 2 * L, blk, 0, stream>>>(flag, Wi, Wj, Wf, Wk2f, Wr1, Wr2, WT, L);
  in_k<<<gridN, blk, 0, stream>>>(flag, x, WT, WT + 17408, bi, bj, mb, xjt, N);
  edge_k<<<gridE, blk, 0, stream>>>(flag, rbf, WT + (size_t)(3 + 2 * L) * 17408,
                                    xjt, idx_i, idx_j, mb, E);
  resid_k<<<gridN, blk, 0, stream>>>(flag, mb, WT, br1, br2, bfv, x, uv, d_out, N, L);
}

// Round 7
// 527.849 us; speedup vs baseline: 1.0431x; 1.0431x over previous
//
#include <hip/hip_runtime.h>
#include <hip/hip_bf16.h>
#include <math.h>

typedef unsigned short u16;
typedef short bf16x8 __attribute__((ext_vector_type(8)));
typedef float f32x4 __attribute__((ext_vector_type(4)));

#define LN2F 0.693147180559945f

__device__ __forceinline__ float bf2f(u16 h) {
  union { unsigned int i; float f; } v; v.i = ((unsigned int)h) << 16; return v.f;
}
__device__ __forceinline__ u16 f2bf(float f) {
  union { float f; unsigned int i; } v; v.f = f;
  unsigned int x = v.i;
  return (u16)((x + 0x7fffu + ((x >> 16) & 1u)) >> 16);
}
// shifted softplus via HW transcendentals (v_exp_f32 + v_log_f32).
__device__ __forceinline__ float sspf(float v) {
  return fmaxf(v, 0.0f) + __logf(1.0f + __expf(-fabsf(v))) - LN2F;
}

// ---------------------------------------------------------------------------
// Dtype probe: bf16 N(0,1) data never has bf16-exponent >= 0xC0; f32 data
// misread as u16 halfwords certainly does.  0 = bf16 inputs, 1 = f32 inputs.
// ---------------------------------------------------------------------------
__global__ void probe_k(const u16* __restrict__ x, int* __restrict__ flag) {
  __shared__ int sf;
  if (threadIdx.x == 0) sf = 0;
  __syncthreads();
  int f = 0;
  for (int i = threadIdx.x; i < 4096; i += 256) {
    const unsigned e = (x[i] >> 7) & 0xFFu;
    if (e >= 0xC0u) f = 1;
  }
  if (f) atomicOr(&sf, 1);
  __syncthreads();
  if (threadIdx.x == 0) *flag = sf;
}

// ---------------------------------------------------------------------------
// Linear 16B-chunk copy (global -> LDS), 256 threads; conflict-free.
// ---------------------------------------------------------------------------
template<int NB>
__device__ __forceinline__ void copy_lin(const u16* __restrict__ g, u16* s, int tid) {
  constexpr int CH = NB / 16;
#pragma unroll
  for (int c = tid; c < CH; c += 256)
    *(bf16x8*)(s + (size_t)c * 8) = *(const bf16x8*)(g + (size_t)c * 8);
}

// 128x136 u16 weight buffer = 2176 16B chunks: reg-staged split (issue loads
// early, ds_write late -> L2 latency hides under activation VALU work).
__device__ __forceinline__ void wload(const u16* __restrict__ g, bf16x8* w, int tid) {
#pragma unroll
  for (int p = 0; p < 8; ++p) w[p] = *(const bf16x8*)(g + (size_t)(tid + p * 256) * 8);
  if (tid < 128) w[8] = *(const bf16x8*)(g + (size_t)(2048 + tid) * 8);
}
__device__ __forceinline__ void wstore(u16* s, const bf16x8* w, int tid) {
#pragma unroll
  for (int p = 0; p < 8; ++p) *(bf16x8*)(s + (size_t)(tid + p * 256) * 8) = w[p];
  if (tid < 128) *(bf16x8*)(s + (size_t)(2048 + tid) * 8) = w[8];
}

// MFMA sweep: acc[t] += sA_strip[m16][k] * sW[t*16+m16][k]
template<int KSTEPS, int LDW>
__device__ __forceinline__ void mm_lds(const u16* sA, const u16* sW, f32x4* acc,
                                       int m16, int quad) {
#pragma unroll
  for (int s = 0; s < KSTEPS; ++s) {
    const int k0 = s * 32 + quad * 8;
    bf16x8 a = *(const bf16x8*)(sA + (size_t)m16 * LDW + k0);
#pragma unroll
    for (int t = 0; t < 8; ++t) {
      bf16x8 b = *(const bf16x8*)(sW + (size_t)(t * 16 + m16) * LDW + k0);
      acc[t] = __builtin_amdgcn_mfma_f32_16x16x32_bf16(a, b, acc[t], 0, 0, 0);
    }
  }
}

// ---------------------------------------------------------------------------
// prep_k: transpose + bf16-convert every weight matrix ONCE into WT (padded).
// WT layout (u16 units): [0]=WiT [17408]=WjT [2*17408]=WfT
//   [ (3+l)*17408 ]   = Wr1T[l]   (each [128][136])
//   [ (3+L+l)*17408 ] = Wr2T[l]
//   [ (3+2L)*17408 ]  = Wk2fT    ([128][72])
// Runtime mode; dtype-dependent loads inside real branches (alternate-dtype
// address ranges can be OOB -> must not be speculated).
// ---------------------------------------------------------------------------
__global__ __launch_bounds__(256) void prep_k(
    const int* __restrict__ mode,
    const void* __restrict__ Wi, const void* __restrict__ Wj,
    const void* __restrict__ Wf, const void* __restrict__ Wk2f,
    const void* __restrict__ Wr1, const void* __restrict__ Wr2,
    u16* __restrict__ WT, int L)
{
  const int md = *mode;
  const int b = blockIdx.x, tid = threadIdx.x;
  const size_t esz = md ? 4 : 2;
  const void* src; u16* dst; int KD = 128, LDW = 136;
  if      (b == 0) { src = Wi;  dst = WT; }
  else if (b == 1) { src = Wj;  dst = WT + 17408; }
  else if (b == 2) { src = Wf;  dst = WT + 2 * 17408; }
  else if (b == 3) { src = Wk2f; dst = WT + (size_t)(3 + 2 * L) * 17408; KD = 64; LDW = 72; }
  else if (b < 4 + L) { int l = b - 4;     src = (const char*)Wr1 + (size_t)l * 16384 * esz; dst = WT + (size_t)(3 + l) * 17408; }
  else                { int l = b - 4 - L; src = (const char*)Wr2 + (size_t)l * 16384 * esz; dst = WT + (size_t)(3 + L + l) * 17408; }

  const int n  = tid & 127;
  const int kh = (tid >> 7) * (KD >> 1);
  if (md == 0) {
    for (int c = 0; c < (KD >> 4); ++c) {
      const int k0 = kh + c * 8;
      bf16x8 rv;
#pragma unroll
      for (int j = 0; j < 8; ++j)
        rv[j] = (short)((const u16*)src)[(size_t)(k0 + j) * 128 + n];
      *(bf16x8*)(dst + (size_t)n * LDW + k0) = rv;
    }
  } else {
    for (int c = 0; c < (KD >> 4); ++c) {
      const int k0 = kh + c * 8;
      bf16x8 rv;
#pragma unroll
      for (int j = 0; j < 8; ++j)
        rv[j] = (short)f2bf(((const float*)src)[(size_t)(k0 + j) * 128 + n]);
      *(bf16x8*)(dst + (size_t)n * LDW + k0) = rv;
    }
  }
}

// ---------------------------------------------------------------------------
// in_k: fused xi/xj input GEMMs.  A = ssp(x) fragments held in regs once.
//   mb  = xi     = ssp(ssp(x)@Wi + bi)   [f32]
//   xjt = xj_all = ssp(ssp(x)@Wj + bj)   [bf16]
// Wj is reg-prefetched during the Wi MFMA sweep.
// ---------------------------------------------------------------------------
__global__ __launch_bounds__(256) void in_k(
    const int* __restrict__ mode, const void* __restrict__ x,
    const u16* __restrict__ WiT, const u16* __restrict__ WjT,
    const void* __restrict__ bi, const void* __restrict__ bj,
    float* __restrict__ mb, u16* __restrict__ xjt, int N)
{
  const int md = *mode;
  __shared__ u16 sW[128 * 136];
  const int tid = threadIdx.x, lane = tid & 63, wave = tid >> 6;
  const int m16 = lane & 15, quad = lane >> 4;
  const int row_tile = blockIdx.x * 64 + wave * 16;
  int arow = row_tile + m16; if (arow >= N) arow = N - 1;

  bf16x8 af[4];
  if (md == 0) {
#pragma unroll
    for (int s = 0; s < 4; ++s) {
      const int k0 = s * 32 + quad * 8;
      bf16x8 raw = *(const bf16x8*)((const u16*)x + (size_t)arow * 128 + k0);
#pragma unroll
      for (int j = 0; j < 8; ++j) af[s][j] = (short)f2bf(sspf(bf2f((u16)raw[j])));
    }
  } else {
#pragma unroll
    for (int s = 0; s < 4; ++s) {
      const int k0 = s * 32 + quad * 8;
      const float* ap = (const float*)x + (size_t)arow * 128 + k0;
      float4 lo = *(const float4*)ap, hi = *(const float4*)(ap + 4);
      float v[8] = {lo.x, lo.y, lo.z, lo.w, hi.x, hi.y, hi.z, hi.w};
#pragma unroll
      for (int j = 0; j < 8; ++j) af[s][j] = (short)f2bf(sspf(v[j]));
    }
  }

  copy_lin<128 * 136 * 2>(WiT, sW, tid);
  __syncthreads();
  f32x4 aI[8], aJ[8];
#pragma unroll
  for (int t = 0; t < 8; ++t) aI[t] = (f32x4){0.f, 0.f, 0.f, 0.f};
  bf16x8 w[9];
  wload(WjT, w, tid);                 // prefetch Wj under the Wi sweep
#pragma unroll
  for (int s = 0; s < 4; ++s) {
    const int k0 = s * 32 + quad * 8;
#pragma unroll
    for (int t = 0; t < 8; ++t) {
      bf16x8 b = *(const bf16x8*)(sW + (size_t)(t * 16 + m16) * 136 + k0);
      aI[t] = __builtin_amdgcn_mfma_f32_16x16x32_bf16(af[s], b, aI[t], 0, 0, 0);
    }
  }
  __syncthreads();
  wstore(sW, w, tid);
  __syncthreads();
#pragma unroll
  for (int t = 0; t < 8; ++t) aJ[t] = (f32x4){0.f, 0.f, 0.f, 0.f};
#pragma unroll
  for (int s = 0; s < 4; ++s) {
    const int k0 = s * 32 + quad * 8;
#pragma unroll
    for (int t = 0; t < 8; ++t) {
      bf16x8 b = *(const bf16x8*)(sW + (size_t)(t * 16 + m16) * 136 + k0);
      aJ[t] = __builtin_amdgcn_mfma_f32_16x16x32_bf16(af[s], b, aJ[t], 0, 0, 0);
    }
  }

#pragma unroll
  for (int t = 0; t < 8; ++t) {
    const int col = t * 16 + m16;
    float biv, bjv;
    if (md == 0) { biv = bf2f(((const u16*)bi)[col]); bjv = bf2f(((const u16*)bj)[col]); }
    else         { biv = ((const float*)bi)[col];     bjv = ((const float*)bj)[col]; }
#pragma unroll
    for (int r = 0; r < 4; ++r) {
      const int ro = row_tile + quad * 4 + r;
      if (ro >= N) continue;
      const size_t off = (size_t)ro * 128 + col;
      mb[off]  = sspf(aI[t][r] + biv);
      xjt[off] = f2bf(sspf(aJ[t][r] + bjv));
    }
  }
}

// ---------------------------------------------------------------------------
// edge_k: one 64-edge tile per block (12500 blocks -> max TLP).  All loads
// issued up-front; B-fragments (Wk2f^T, 18.4 KB shared by ALL blocks ->
// L1-resident per CU) streamed straight from global -- no LDS weight
// staging, no staging barrier.  msg = g*xj computed in registers; only the
// scan transpose goes through LDS (17.2 KB, 0 bank conflicts).
// NO min-waves bound: R6 showed __launch_bounds__(256,6) caps VGPR at ~85
// and spills (~115 MB scratch HBM traffic, +45 us).  Natural allocation
// ~105 VGPR -> 4-5 blocks/CU, spill-free.
// ---------------------------------------------------------------------------
__global__ __launch_bounds__(256) void edge_k(
    const int* __restrict__ mode,
    const void* __restrict__ rbf, const u16* __restrict__ WkT,
    const u16* __restrict__ xj_all, const int* __restrict__ idx_i,
    const int* __restrict__ idx_j, float* __restrict__ mb, int E)
{
  const int md = *mode;
  __shared__ u16 sMsg[64][132];
  __shared__ int sIi[64];
  const int tid = threadIdx.x;
  const int e0 = blockIdx.x * 64;
  const int lane = tid & 63, wave = tid >> 6;
  const int m16 = lane & 15, quad = lane >> 4;
  const int lebase = wave * 16 + quad * 4;   // this lane's 4 owned edge rows

  if (tid < 64) sIi[tid] = (e0 + tid < E) ? idx_i[e0 + tid] : -1;
  int jrow[4];
#pragma unroll
  for (int r = 0; r < 4; ++r) {
    const int e = e0 + lebase + r;
    jrow[r] = (e < E) ? idx_j[e] : 0;        // broadcast-cached 4B loads
  }

  // rbf A-fragments into regs (convert to bf16 at load in f32 mode)
  int er = e0 + wave * 16 + m16; if (er >= E) er = E - 1;
  bf16x8 rb[2];
  if (md == 0) {
    const u16* p = (const u16*)rbf + (size_t)er * 64 + quad * 8;
    rb[0] = *(const bf16x8*)p;
    rb[1] = *(const bf16x8*)(p + 32);
  } else {
    const float* p = (const float*)rbf + (size_t)er * 64 + quad * 8;
    float4 a0 = *(const float4*)p,        a1 = *(const float4*)(p + 4);
    float4 a2 = *(const float4*)(p + 32), a3 = *(const float4*)(p + 36);
    rb[0][0] = f2bf(a0.x); rb[0][1] = f2bf(a0.y); rb[0][2] = f2bf(a0.z); rb[0][3] = f2bf(a0.w);
    rb[0][4] = f2bf(a1.x); rb[0][5] = f2bf(a1.y); rb[0][6] = f2bf(a1.z); rb[0][7] = f2bf(a1.w);
    rb[1][0] = f2bf(a2.x); rb[1][1] = f2bf(a2.y); rb[1][2] = f2bf(a2.z); rb[1][3] = f2bf(a2.w);
    rb[1][4] = f2bf(a3.x); rb[1][5] = f2bf(a3.y); rb[1][6] = f2bf(a3.z); rb[1][7] = f2bf(a3.w);
  }

  // gather xj directly in C-fragment layout (32 x 2B per lane, L2/L3-hot)
  u16 xg[8][4];
#pragma unroll
  for (int r = 0; r < 4; ++r) {
    const u16* xr = xj_all + (size_t)jrow[r] * 128 + m16;
#pragma unroll
    for (int t = 0; t < 8; ++t) xg[t][r] = xr[t * 16];
  }

  // MFMA: g = rbf @ Wk2f, B-fragments streamed from global (L1-hot)
  f32x4 acc[8];
#pragma unroll
  for (int t = 0; t < 8; ++t) acc[t] = (f32x4){0.f, 0.f, 0.f, 0.f};
  const u16* wp = WkT + (size_t)m16 * 72 + quad * 8;
#pragma unroll
  for (int s = 0; s < 2; ++s) {
#pragma unroll
    for (int t = 0; t < 8; ++t) {
      bf16x8 b = *(const bf16x8*)(wp + (size_t)(t * 16) * 72 + s * 32);
      acc[t] = __builtin_amdgcn_mfma_f32_16x16x32_bf16(rb[s], b, acc[t], 0, 0, 0);
    }
  }

  // msg = g * xj in registers; write owner slots to sMsg for the scan
#pragma unroll
  for (int t = 0; t < 8; ++t) {
    const int col = t * 16 + m16;
#pragma unroll
    for (int r = 0; r < 4; ++r) {
      const float xvf = (e0 + lebase + r < E) ? bf2f(xg[t][r]) : 0.f;
      sMsg[lebase + r][col] = f2bf(acc[t][r] * xvf);
    }
  }
  __syncthreads();

  // segment scan over sorted idx_i; boundary atomics
  const int scol = tid & 127;
  const int sbeg = (tid >> 7) * 32;
  float sum = 0.f;
  int cur = sIi[sbeg];
#pragma unroll 4
  for (int r = 0; r < 32; ++r) {
    const int node = sIi[sbeg + r];
    if (node != cur) {
      if (cur >= 0) atomicAdd(&mb[(size_t)cur * 128 + scol], sum);
      sum = 0.f; cur = node;
    }
    sum += bf2f(sMsg[sbeg + r][scol]);
  }
  if (cur >= 0) atomicAdd(&mb[(size_t)cur * 128 + scol], sum);
}

// ---------------------------------------------------------------------------
// resid_k: fused residual chain + final output, 64 rows/block (782 blocks,
// 52224 B LDS -> 3 blocks/CU).  m stays in MFMA C-fragments.  Per phase:
// issue next weight's global loads -> ssp into sM -> ds_write weight ->
// barrier -> MFMA sweep.  Load latency hides under ssp.
// ---------------------------------------------------------------------------
__global__ __launch_bounds__(256) void resid_k(
    const int* __restrict__ mode, const float* __restrict__ mb,
    const u16* __restrict__ WT,
    const void* __restrict__ br1, const void* __restrict__ br2,
    const void* __restrict__ bfv, const void* __restrict__ x,
    const void* __restrict__ u, void* __restrict__ out, int N, int L)
{
  const int md = *mode;
  __shared__ u16 sW[128 * 136];
  __shared__ u16 sM[64 * 136];
  const int tid = threadIdx.x, lane = tid & 63, wave = tid >> 6;
  const int m16 = lane & 15, quad = lane >> 4;
  const int rbase = blockIdx.x * 64 + wave * 16 + quad * 4;
  u16* sMw = sM + (size_t)(wave * 16) * 136;   // wave's 16-row strip

  f32x4 m[8];
#pragma unroll
  for (int t = 0; t < 8; ++t) {
    const int col = t * 16 + m16;
#pragma unroll
    for (int r = 0; r < 4; ++r) {
      int ro = rbase + r; if (ro >= N) ro = N - 1;
      m[t][r] = mb[(size_t)ro * 128 + col];
    }
  }

  const u16* W1T = WT + (size_t)3 * 17408;
  const u16* W2T = WT + (size_t)(3 + L) * 17408;
  bf16x8 w[9];

  for (int l = 0; l < L; ++l) {
    // phase A: sM := ssp(m); sW := W1 (loads issued before the ssp block)
    wload(W1T + (size_t)l * 17408, w, tid);
#pragma unroll
    for (int t = 0; t < 8; ++t) {
      const int col = t * 16 + m16;
#pragma unroll
      for (int r = 0; r < 4; ++r)
        sM[(size_t)(wave * 16 + quad * 4 + r) * 136 + col] = f2bf(sspf(m[t][r]));
    }
    wstore(sW, w, tid);
    __syncthreads();

    f32x4 a1[8];
#pragma unroll
    for (int t = 0; t < 8; ++t) a1[t] = (f32x4){0.f, 0.f, 0.f, 0.f};
    mm_lds<4, 136>(sMw, sW, a1, m16, quad);
    __syncthreads();

    // phase B: sM := ssp(a1 + b1); sW := W2
    wload(W2T + (size_t)l * 17408, w, tid);
#pragma unroll
    for (int t = 0; t < 8; ++t) {
      const int col = t * 16 + m16;
      float b1v;
      if (md == 0) b1v = bf2f(((const u16*)br1)[(size_t)l * 128 + col]);
      else         b1v = ((const float*)br1)[(size_t)l * 128 + col];
#pragma unroll
      for (int r = 0; r < 4; ++r)
        sM[(size_t)(wave * 16 + quad * 4 + r) * 136 + col] = f2bf(sspf(a1[t][r] + b1v));
    }
    wstore(sW, w, tid);
    __syncthreads();

    mm_lds<4, 136>(sMw, sW, m, m16, quad);   // m += t1 @ W2
#pragma unroll
    for (int t = 0; t < 8; ++t) {
      float b2v;
      if (md == 0) b2v = bf2f(((const u16*)br2)[(size_t)l * 128 + t * 16 + m16]);
      else         b2v = ((const float*)br2)[(size_t)l * 128 + t * 16 + m16];
#pragma unroll
      for (int r = 0; r < 4; ++r) m[t][r] += b2v;
    }
    __syncthreads();   // reads done before next phase's staging
  }

  // final: out = u*x + ssp(m)@Wf + bf
  wload(WT + (size_t)2 * 17408, w, tid);   // WfT
#pragma unroll
  for (int t = 0; t < 8; ++t) {
    const int col = t * 16 + m16;
#pragma unroll
    for (int r = 0; r < 4; ++r)
      sM[(size_t)(wave * 16 + quad * 4 + r) * 136 + col] = f2bf(sspf(m[t][r]));
  }
  wstore(sW, w, tid);
  __syncthreads();

  f32x4 o[8];
#pragma unroll
  for (int t = 0; t < 8; ++t) o[t] = (f32x4){0.f, 0.f, 0.f, 0.f};
  mm_lds<4, 136>(sMw, sW, o, m16, quad);

#pragma unroll
  for (int t = 0; t < 8; ++t) {
    const int col = t * 16 + m16;
    float bv, uvv;
    if (md == 0) { bv = bf2f(((const u16*)bfv)[col]); uvv = bf2f(((const u16*)u)[col]); }
    else         { bv = ((const float*)bfv)[col];     uvv = ((const float*)u)[col]; }
#pragma unroll
    for (int r = 0; r < 4; ++r) {
      const int ro = rbase + r;
      if (ro >= N) continue;
      const size_t off = (size_t)ro * 128 + col;
      if (md == 0) ((u16*)out)[off]  = f2bf(uvv * bf2f(((const u16*)x)[off]) + o[t][r] + bv);
      else         ((float*)out)[off] = uvv * ((const float*)x)[off] + o[t][r] + bv;
    }
  }
}

// ---------------------------------------------------------------------------
extern "C" void kernel_launch(void* const* d_in, const int* in_sizes, int n_in,
                              void* d_out, int out_size, void* d_ws, size_t ws_size,
                              hipStream_t stream)
{
  const void* x    = d_in[0];
  const void* rbf  = d_in[1];
  const void* Wk2f = d_in[2];
  const void* Wi   = d_in[3];
  const void* bi   = d_in[4];
  const void* Wj   = d_in[5];
  const void* bj   = d_in[6];
  const void* Wr1  = d_in[7];
  const void* br1  = d_in[8];
  const void* Wr2  = d_in[9];
  const void* br2  = d_in[10];
  const void* Wf   = d_in[11];
  const void* bfv  = d_in[12];
  const void* uv   = d_in[13];
  const int* idx_i = (const int*)d_in[14];
  const int* idx_j = (const int*)d_in[15];

  const int N = in_sizes[0] / 128;
  const int E = in_sizes[14];
  const int L = in_sizes[7] / (128 * 128);

  int* flag = (int*)d_ws;
  char* wsb = (char*)d_ws + 16;
  const size_t avail = ws_size > 16 ? ws_size - 16 : 0;

  // pre-transposed weight area (bf16, padded strides)
  const size_t needW  = ((size_t)(3 + 2 * L) * 17408 + 9216) * 2;
  const size_t needWA = (needW + 255) & ~(size_t)255;
  u16* WT = (u16*)wsb;
  char* wsb2 = wsb + needWA;
  const size_t avail2 = (avail > needWA) ? avail - needWA : 0;

  const size_t needF = (size_t)N * 512;   // mb f32
  const size_t needH = (size_t)N * 256;   // xj_all bf16

  float* mb; u16* xjt;
  if (avail2 >= needF + needH) { mb = (float*)wsb2; xjt = (u16*)(wsb2 + needF); }
  else if (avail2 >= needF)    { mb = (float*)wsb2; xjt = (u16*)d_out; }
  else                         { mb = (float*)d_out; xjt = (u16*)wsb2; }

  const dim3 blk(256);
  const int gridN = (N + 63) / 64;
  const int gridE = (E + 63) / 64;

  probe_k<<<1, 256, 0, stream>>>((const u16*)x, flag);
  prep_k<<<4 + 2 * L, blk, 0, stream>>>(flag, Wi, Wj, Wf, Wk2f, Wr1, Wr2, WT, L);
  in_k<<<gridN, blk, 0, stream>>>(flag, x, WT, WT + 17408, bi, bj, mb, xjt, N);
  edge_k<<<gridE, blk, 0, stream>>>(flag, rbf, WT + (size_t)(3 + 2 * L) * 17408,
                                    xjt, idx_i, idx_j, mb, E);
  resid_k<<<gridN, blk, 0, stream>>>(flag, mb, WT, br1, br2, bfv, x, uv, d_out, N, L);
}